// Round 1
// baseline (747.931 us; speedup 1.0000x reference)
//
#include <hip/hip_runtime.h>
#include <math.h>

// ---------------------------------------------------------------------------
// GCN 3-layer: h = relu(Agg(x@W1)+b1); h = relu(Agg(h@W2)+b2);
//              out = log_softmax(Agg(h@W3)+b3)
// Agg(h)[i] = sum_{e: dst=i} h[src_e]*dinv[src]*dinv[i] + h[i]*dinv[i]^2
// dinv[i] = rsqrt(in_deg[i] + 1)   (self-loop included)
// Strategy: build CSR by dst each call (int atomics), then atomic-free
// per-node aggregation with coalesced feature reads. f32 tiled GEMM (no
// fp32 MFMA on CDNA4).
// ---------------------------------------------------------------------------

#define NFEAT 512
#define NHID  128
#define NCLS  64

__global__ void zero_int_kernel(int* __restrict__ p, int n) {
  int i = blockIdx.x * 256 + threadIdx.x;
  if (i < n) p[i] = 0;
}

__global__ void count_kernel(const int* __restrict__ dst, int* __restrict__ cnt, int E) {
  int e = blockIdx.x * 256 + threadIdx.x;
  if (e < E) atomicAdd(&cnt[dst[e]], 1);
}

__global__ void dinv_kernel(const int* __restrict__ cnt, float* __restrict__ dinv, int N) {
  int i = blockIdx.x * 256 + threadIdx.x;
  if (i < N) dinv[i] = rsqrtf((float)(cnt[i] + 1));  // deg >= 1 always (self-loop)
}

// single-block exclusive scan over cnt[0..N) -> row_ptr, pos
__global__ void scan_kernel(const int* __restrict__ cnt, int* __restrict__ row_ptr,
                            int* __restrict__ pos, int N, int E) {
  __shared__ int part[1024];
  int tid = threadIdx.x;
  int chunk = (N + 1023) >> 10;
  int beg = tid * chunk;
  int end = min(beg + chunk, N);
  int s = 0;
  for (int i = beg; i < end; ++i) s += cnt[i];
  part[tid] = s;
  __syncthreads();
  for (int off = 1; off < 1024; off <<= 1) {
    int v = (tid >= off) ? part[tid - off] : 0;
    __syncthreads();
    part[tid] += v;
    __syncthreads();
  }
  int run = part[tid] - s;  // exclusive prefix of this thread's chunk
  for (int i = beg; i < end; ++i) {
    row_ptr[i] = run;
    pos[i] = run;
    run += cnt[i];
  }
  if (tid == 0) row_ptr[N] = E;
}

__global__ void fill_kernel(const int* __restrict__ src, const int* __restrict__ dst,
                            int* __restrict__ pos, int* __restrict__ col, int E) {
  int e = blockIdx.x * 256 + threadIdx.x;
  if (e < E) {
    int p = atomicAdd(&pos[dst[e]], 1);
    col[p] = src[e];
  }
}

// ---------------------------------------------------------------------------
// Tiled f32 GEMM: C[M,BN] = A[M,K] @ W[K,BN].  BN == full output width.
// ---------------------------------------------------------------------------
template <int BM, int BN, int BK, int TM, int TN>
__global__ void gemm_kernel(const float* __restrict__ A, const float* __restrict__ W,
                            float* __restrict__ C, int M, int K) {
  constexpr int THREADS = (BM / TM) * (BN / TN);
  __shared__ float As[BK][BM];
  __shared__ float Bs[BK][BN];
  const int tid = threadIdx.x;
  const int tc = tid % (BN / TN);
  const int tr = tid / (BN / TN);
  const int block_row = blockIdx.x * BM;

  float acc[TM][TN];
#pragma unroll
  for (int i = 0; i < TM; ++i)
#pragma unroll
    for (int j = 0; j < TN; ++j) acc[i][j] = 0.f;

  for (int k0 = 0; k0 < K; k0 += BK) {
    // A tile: BM x BK, float4 loads, store transposed As[k][m]
    constexpr int A_LOADS = (BM * BK) / (THREADS * 4);
#pragma unroll
    for (int l = 0; l < A_LOADS; ++l) {
      int idx = tid + l * THREADS;           // float4 index
      int r = idx / (BK / 4);
      int c4 = idx % (BK / 4);
      int grow = block_row + r;
      float4 v = make_float4(0.f, 0.f, 0.f, 0.f);
      if (grow < M) v = *reinterpret_cast<const float4*>(&A[(size_t)grow * K + k0 + c4 * 4]);
      As[c4 * 4 + 0][r] = v.x;
      As[c4 * 4 + 1][r] = v.y;
      As[c4 * 4 + 2][r] = v.z;
      As[c4 * 4 + 3][r] = v.w;
    }
    // B tile: BK x BN
    constexpr int B_LOADS = (BK * BN) / (THREADS * 4);
#pragma unroll
    for (int l = 0; l < B_LOADS; ++l) {
      int idx = tid + l * THREADS;
      int r = idx / (BN / 4);
      int c4 = idx % (BN / 4);
      *reinterpret_cast<float4*>(&Bs[r][c4 * 4]) =
          *reinterpret_cast<const float4*>(&W[(size_t)(k0 + r) * BN + c4 * 4]);
    }
    __syncthreads();
#pragma unroll
    for (int kk = 0; kk < BK; ++kk) {
      float a[TM], bb[TN];
#pragma unroll
      for (int i = 0; i < TM; ++i) a[i] = As[kk][tr * TM + i];
#pragma unroll
      for (int j = 0; j < TN; ++j) bb[j] = Bs[kk][tc * TN + j];
#pragma unroll
      for (int i = 0; i < TM; ++i)
#pragma unroll
        for (int j = 0; j < TN; ++j) acc[i][j] += a[i] * bb[j];
    }
    __syncthreads();
  }
#pragma unroll
  for (int i = 0; i < TM; ++i) {
    int grow = block_row + tr * TM + i;
    if (grow < M) {
#pragma unroll
      for (int j = 0; j < TN; j += 4) {
        float4 v = make_float4(acc[i][j], acc[i][j + 1], acc[i][j + 2], acc[i][j + 3]);
        *reinterpret_cast<float4*>(&C[(size_t)grow * BN + tc * TN + j]) = v;
      }
    }
  }
}

// ---------------------------------------------------------------------------
// Aggregation: out[i] = op( sum_{j in row[i]} H[col[j]]*dinv[col[j]]*dinv[i]
//                           + H[i]*dinv[i]^2 + bias )
// ---------------------------------------------------------------------------
template <int F, int RELU>
__global__ void agg_kernel(const float* __restrict__ H, const int* __restrict__ row_ptr,
                           const int* __restrict__ col, const float* __restrict__ dinv,
                           const float* __restrict__ bias, float* __restrict__ out, int N) {
  constexpr int NPB = 256 / F;
  const int tid = threadIdx.x;
  const int f = tid % F;
  const int node = blockIdx.x * NPB + tid / F;
  if (node >= N) return;
  const float di = dinv[node];
  float s = H[(size_t)node * F + f] * di * di;  // self-loop
  const int beg = row_ptr[node];
  const int end = row_ptr[node + 1];
  for (int j = beg; j < end; ++j) {
    int sc = col[j];
    float w = dinv[sc] * di;
    s += H[(size_t)sc * F + f] * w;
  }
  s += bias[f];
  if (RELU) s = fmaxf(s, 0.f);
  out[(size_t)node * F + f] = s;
}

__global__ void logsoftmax_kernel(const float* __restrict__ H, float* __restrict__ out, int N) {
  const int lane = threadIdx.x & 63;
  const int row = blockIdx.x * 4 + (threadIdx.x >> 6);
  if (row >= N) return;
  float v = H[(size_t)row * NCLS + lane];
  float m = v;
#pragma unroll
  for (int off = 32; off > 0; off >>= 1) m = fmaxf(m, __shfl_xor(m, off));
  float e = expf(v - m);
  float ssum = e;
#pragma unroll
  for (int off = 32; off > 0; off >>= 1) ssum += __shfl_xor(ssum, off);
  out[(size_t)row * NCLS + lane] = (v - m) - logf(ssum);
}

extern "C" void kernel_launch(void* const* d_in, const int* in_sizes, int n_in,
                              void* d_out, int out_size, void* d_ws, size_t ws_size,
                              hipStream_t stream) {
  const float* x  = (const float*)d_in[0];
  const int*   ei = (const int*)d_in[1];
  const float* W1 = (const float*)d_in[2];
  const float* b1 = (const float*)d_in[3];
  const float* W2 = (const float*)d_in[4];
  const float* b2 = (const float*)d_in[5];
  const float* W3 = (const float*)d_in[6];
  const float* b3 = (const float*)d_in[7];
  float* out = (float*)d_out;

  const int N = in_sizes[0] / NFEAT;  // 50000
  const int E = in_sizes[1] / 2;      // 800000
  const int* src = ei;
  const int* dst = ei + E;

  char* ws = (char*)d_ws;
  size_t off = 0;
  auto nxt = [&](size_t bytes) -> void* {
    void* p = ws + off;
    off += (bytes + 255) & ~(size_t)255;
    return p;
  };
  int*   cnt     = (int*)nxt((size_t)N * 4);
  int*   pos     = (int*)nxt((size_t)N * 4);
  int*   row_ptr = (int*)nxt((size_t)(N + 1) * 4);
  int*   col     = (int*)nxt((size_t)E * 4);
  float* dinv    = (float*)nxt((size_t)N * 4);
  float* bufA    = (float*)nxt((size_t)N * NHID * 4);
  float* bufB    = (float*)nxt((size_t)N * NHID * 4);
  (void)ws_size; (void)n_in; (void)out_size;

  // --- CSR + norm setup (recomputed every call; no persistent state) ---
  zero_int_kernel<<<(N + 255) / 256, 256, 0, stream>>>(cnt, N);
  count_kernel<<<(E + 255) / 256, 256, 0, stream>>>(dst, cnt, E);
  dinv_kernel<<<(N + 255) / 256, 256, 0, stream>>>(cnt, dinv, N);
  scan_kernel<<<1, 1024, 0, stream>>>(cnt, row_ptr, pos, N, E);
  fill_kernel<<<(E + 255) / 256, 256, 0, stream>>>(src, dst, pos, col, E);

  // --- layer 1: [N,512]@[512,128] -> agg+relu ---
  gemm_kernel<64, 128, 32, 8, 4><<<(N + 63) / 64, 256, 0, stream>>>(x, W1, bufA, N, NFEAT);
  agg_kernel<128, 1><<<(N + 1) / 2, 256, 0, stream>>>(bufA, row_ptr, col, dinv, b1, bufB, N);

  // --- layer 2: [N,128]@[128,128] -> agg+relu ---
  gemm_kernel<64, 128, 32, 8, 4><<<(N + 63) / 64, 256, 0, stream>>>(bufB, W2, bufA, N, NHID);
  agg_kernel<128, 1><<<(N + 1) / 2, 256, 0, stream>>>(bufA, row_ptr, col, dinv, b2, bufB, N);

  // --- layer 3: [N,128]@[128,64] -> agg (no relu) -> log_softmax ---
  gemm_kernel<64, 64, 32, 8, 4><<<(N + 63) / 64, 128, 0, stream>>>(bufB, W3, bufA, N, NHID);
  agg_kernel<64, 0><<<(N + 3) / 4, 256, 0, stream>>>(bufA, row_ptr, col, dinv, b3, bufB, N);
  logsoftmax_kernel<<<(N + 3) / 4, 256, 0, stream>>>(bufB, out, N);
}

// Round 2
// 424.676 us; speedup vs baseline: 1.7612x; 1.7612x over previous
//
#include <hip/hip_runtime.h>
#include <math.h>

// ---------------------------------------------------------------------------
// GCN 3-layer on MI355X.
//   h = relu(Agg(x@W1)+b1); h = relu(Agg(h@W2)+b2); out = log_softmax(Agg(h@W3)+b3)
// GEMMs: bf16 MFMA (16x16x32), inputs cast to bf16 (inline for A, prepass
// transpose+cast for W), f32 accumulate, f32 output.
// Agg: CSR built per call (atomics), then atomic-free per-node gather,
// float4-vectorized, 2-wide unrolled.
// ---------------------------------------------------------------------------

#define NFEAT 512
#define NHID  128
#define NCLS  64

typedef __attribute__((ext_vector_type(8))) short bf16x8;
typedef __attribute__((ext_vector_type(8))) unsigned short u16x8;
typedef __attribute__((ext_vector_type(4))) float f32x4;

__device__ __forceinline__ unsigned short f2bf(float f) {
  unsigned u = __builtin_bit_cast(unsigned, f);
  unsigned r = (u + 0x7FFFu + ((u >> 16) & 1u)) >> 16;
  return (unsigned short)r;
}

// ------------------------------ CSR setup ----------------------------------
__global__ void zero_int_kernel(int* __restrict__ p, int n) {
  int i = blockIdx.x * 256 + threadIdx.x;
  if (i < n) p[i] = 0;
}

__global__ void count_kernel(const int* __restrict__ dst, int* __restrict__ cnt, int E) {
  int e = blockIdx.x * 256 + threadIdx.x;
  if (e < E) atomicAdd(&cnt[dst[e]], 1);
}

__global__ void dinv_kernel(const int* __restrict__ cnt, float* __restrict__ dinv, int N) {
  int i = blockIdx.x * 256 + threadIdx.x;
  if (i < N) dinv[i] = rsqrtf((float)(cnt[i] + 1));
}

__global__ void scan_kernel(const int* __restrict__ cnt, int* __restrict__ row_ptr,
                            int* __restrict__ pos, int N, int E) {
  __shared__ int part[1024];
  int tid = threadIdx.x;
  int chunk = (N + 1023) >> 10;
  int beg = tid * chunk;
  int end = min(beg + chunk, N);
  int s = 0;
  for (int i = beg; i < end; ++i) s += cnt[i];
  part[tid] = s;
  __syncthreads();
  for (int off = 1; off < 1024; off <<= 1) {
    int v = (tid >= off) ? part[tid - off] : 0;
    __syncthreads();
    part[tid] += v;
    __syncthreads();
  }
  int run = part[tid] - s;
  for (int i = beg; i < end; ++i) {
    row_ptr[i] = run;
    pos[i] = run;
    run += cnt[i];
  }
  if (tid == 0) row_ptr[N] = E;
}

__global__ void fill_kernel(const int* __restrict__ src, const int* __restrict__ dst,
                            int* __restrict__ pos, int* __restrict__ col, int E) {
  int e = blockIdx.x * 256 + threadIdx.x;
  if (e < E) {
    int p = atomicAdd(&pos[dst[e]], 1);
    col[p] = src[e];
  }
}

// --------------------- W transpose + cast prepass --------------------------
// W [K,N] f32 row-major  ->  Wt [N,K] bf16 row-major
__global__ void wcast_kernel(const float* __restrict__ W, unsigned short* __restrict__ Wt,
                             int K, int N) {
  int idx = blockIdx.x * 256 + threadIdx.x;
  if (idx >= N * K) return;
  int n = idx / K;
  int k = idx - n * K;
  Wt[idx] = f2bf(W[(size_t)k * N + n]);
}

// --------------------------- bf16 MFMA GEMM --------------------------------
// C[M,BN] = A[M,K](f32, cast inline) @ Wt[BN,K](bf16, pre-transposed)
// BM=64, BK=64, 4 waves (2x2), wave tile 32 x BN/2.
template <int BN>
__global__ void mfma_gemm_kernel(const float* __restrict__ A,
                                 const unsigned short* __restrict__ Wt,
                                 float* __restrict__ C, int M, int K) {
  constexpr int BM = 64, BK = 64;
  constexpr int NF = BN / 32;  // 16-wide n-frags per wave
  __shared__ unsigned short Al[BM * BK];  // [row][k], XOR-swizzled
  __shared__ unsigned short Bl[BN * BK];  // [n][k],  XOR-swizzled
  const int tid = threadIdx.x;
  const int lane = tid & 63;
  const int wave = tid >> 6;
  const int wm = wave >> 1, wn = wave & 1;
  const int block_row = blockIdx.x * BM;

  f32x4 acc[2][NF];
#pragma unroll
  for (int i = 0; i < 2; ++i)
#pragma unroll
    for (int j = 0; j < NF; ++j) acc[i][j] = (f32x4){0.f, 0.f, 0.f, 0.f};

  for (int k0 = 0; k0 < K; k0 += BK) {
    // ---- stage A (f32 -> bf16, swizzled) ----
    {
      const int r = tid >> 2;            // 64 rows, 4 threads each
      const int c0 = (tid & 3) * 16;     // 16 elems per thread
      const int grow = block_row + r;
      float4 v[4];
      if (grow < M) {
        const float4* p = reinterpret_cast<const float4*>(&A[(size_t)grow * K + k0 + c0]);
        v[0] = p[0]; v[1] = p[1]; v[2] = p[2]; v[3] = p[3];
      } else {
        v[0] = v[1] = v[2] = v[3] = make_float4(0.f, 0.f, 0.f, 0.f);
      }
      unsigned short t[16];
#pragma unroll
      for (int q = 0; q < 4; ++q) {
        t[q * 4 + 0] = f2bf(v[q].x); t[q * 4 + 1] = f2bf(v[q].y);
        t[q * 4 + 2] = f2bf(v[q].z); t[q * 4 + 3] = f2bf(v[q].w);
      }
#pragma unroll
      for (int h = 0; h < 2; ++h) {
        int c = c0 + h * 8;
        int byte = r * 128 + c * 2;
        byte ^= (r & 7) << 4;
        u16x8 pk;
#pragma unroll
        for (int q = 0; q < 8; ++q) pk[q] = t[h * 8 + q];
        *reinterpret_cast<u16x8*>(reinterpret_cast<char*>(Al) + byte) = pk;
      }
    }
    // ---- stage B (bf16 copy, swizzled) ----
    {
      constexpr int NVEC = BN * BK / 8;  // u16x8 vectors total
#pragma unroll
      for (int l = 0; l < NVEC / 256; ++l) {
        int vidx = tid + l * 256;
        int n = vidx >> 3;                // BK/8 = 8 vecs per row
        int kc = (vidx & 7) * 8;
        u16x8 pk = *reinterpret_cast<const u16x8*>(&Wt[(size_t)n * K + k0 + kc]);
        int byte = n * 128 + kc * 2;
        byte ^= (n & 7) << 4;
        *reinterpret_cast<u16x8*>(reinterpret_cast<char*>(Bl) + byte) = pk;
      }
    }
    __syncthreads();
    // ---- compute ----
#pragma unroll
    for (int kk = 0; kk < 2; ++kk) {
      const int kb = kk * 32 + (lane >> 4) * 8;
      bf16x8 af[2], bfr[NF];
#pragma unroll
      for (int mf = 0; mf < 2; ++mf) {
        int r = wm * 32 + mf * 16 + (lane & 15);
        int byte = r * 128 + kb * 2;
        byte ^= (r & 7) << 4;
        af[mf] = *reinterpret_cast<bf16x8*>(reinterpret_cast<char*>(Al) + byte);
      }
#pragma unroll
      for (int nf = 0; nf < NF; ++nf) {
        int n = wn * (BN / 2) + nf * 16 + (lane & 15);
        int byte = n * 128 + kb * 2;
        byte ^= (n & 7) << 4;
        bfr[nf] = *reinterpret_cast<bf16x8*>(reinterpret_cast<char*>(Bl) + byte);
      }
#pragma unroll
      for (int mf = 0; mf < 2; ++mf)
#pragma unroll
        for (int nf = 0; nf < NF; ++nf)
          acc[mf][nf] = __builtin_amdgcn_mfma_f32_16x16x32_bf16(af[mf], bfr[nf], acc[mf][nf], 0, 0, 0);
    }
    __syncthreads();
  }
  // ---- epilogue: f32 store ----
#pragma unroll
  for (int mf = 0; mf < 2; ++mf) {
#pragma unroll
    for (int nf = 0; nf < NF; ++nf) {
#pragma unroll
      for (int r = 0; r < 4; ++r) {
        int row = block_row + wm * 32 + mf * 16 + (lane >> 4) * 4 + r;
        int colc = wn * (BN / 2) + nf * 16 + (lane & 15);
        if (row < M) C[(size_t)row * BN + colc] = acc[mf][nf][r];
      }
    }
  }
}

// ----------------------------- aggregation ---------------------------------
// out[i] = op( sum_j H[col[j]]*dinv[col[j]]*dinv[i] + H[i]*dinv[i]^2 + bias )
template <int F, int RELU>
__global__ void agg_kernel(const float* __restrict__ H, const int* __restrict__ row_ptr,
                           const int* __restrict__ col, const float* __restrict__ dinv,
                           const float* __restrict__ bias, float* __restrict__ out, int N) {
  constexpr int LPN = F / 4;        // lanes per node (float4)
  constexpr int NPB = 256 / LPN;
  const int tid = threadIdx.x;
  const int li = tid % LPN;
  const int node = blockIdx.x * NPB + tid / LPN;
  if (node >= N) return;
  const float di = dinv[node];
  const float4* Hv = reinterpret_cast<const float4*>(H);
  float4 h0 = Hv[(size_t)node * LPN + li];
  const float w0 = di * di;
  float sx = h0.x * w0, sy = h0.y * w0, sz = h0.z * w0, sw = h0.w * w0;
  const int beg = row_ptr[node];
  const int end = row_ptr[node + 1];
  int j = beg;
  for (; j + 1 < end; j += 2) {
    int sa = col[j];
    int sb = col[j + 1];
    float wa = dinv[sa] * di;
    float wb = dinv[sb] * di;
    float4 ha = Hv[(size_t)sa * LPN + li];
    float4 hb = Hv[(size_t)sb * LPN + li];
    sx += ha.x * wa; sy += ha.y * wa; sz += ha.z * wa; sw += ha.w * wa;
    sx += hb.x * wb; sy += hb.y * wb; sz += hb.z * wb; sw += hb.w * wb;
  }
  if (j < end) {
    int sa = col[j];
    float wa = dinv[sa] * di;
    float4 ha = Hv[(size_t)sa * LPN + li];
    sx += ha.x * wa; sy += ha.y * wa; sz += ha.z * wa; sw += ha.w * wa;
  }
  float4 b = reinterpret_cast<const float4*>(bias)[li];
  sx += b.x; sy += b.y; sz += b.z; sw += b.w;
  if (RELU) {
    sx = fmaxf(sx, 0.f); sy = fmaxf(sy, 0.f);
    sz = fmaxf(sz, 0.f); sw = fmaxf(sw, 0.f);
  }
  float4 o; o.x = sx; o.y = sy; o.z = sz; o.w = sw;
  reinterpret_cast<float4*>(out)[(size_t)node * LPN + li] = o;
}

__global__ void logsoftmax_kernel(const float* __restrict__ H, float* __restrict__ out, int N) {
  const int lane = threadIdx.x & 63;
  const int row = blockIdx.x * 4 + (threadIdx.x >> 6);
  if (row >= N) return;
  float v = H[(size_t)row * NCLS + lane];
  float m = v;
#pragma unroll
  for (int off = 32; off > 0; off >>= 1) m = fmaxf(m, __shfl_xor(m, off));
  float e = expf(v - m);
  float ssum = e;
#pragma unroll
  for (int off = 32; off > 0; off >>= 1) ssum += __shfl_xor(ssum, off);
  out[(size_t)row * NCLS + lane] = (v - m) - logf(ssum);
}

// ---------------------------------------------------------------------------
extern "C" void kernel_launch(void* const* d_in, const int* in_sizes, int n_in,
                              void* d_out, int out_size, void* d_ws, size_t ws_size,
                              hipStream_t stream) {
  const float* x  = (const float*)d_in[0];
  const int*   ei = (const int*)d_in[1];
  const float* W1 = (const float*)d_in[2];
  const float* b1 = (const float*)d_in[3];
  const float* W2 = (const float*)d_in[4];
  const float* b2 = (const float*)d_in[5];
  const float* W3 = (const float*)d_in[6];
  const float* b3 = (const float*)d_in[7];
  float* out = (float*)d_out;

  const int N = in_sizes[0] / NFEAT;  // 50000
  const int E = in_sizes[1] / 2;      // 800000
  const int* src = ei;
  const int* dst = ei + E;

  char* ws = (char*)d_ws;
  size_t off = 0;
  auto nxt = [&](size_t bytes) -> void* {
    void* p = ws + off;
    off += (bytes + 255) & ~(size_t)255;
    return p;
  };
  int*   cnt     = (int*)nxt((size_t)N * 4);
  int*   pos     = (int*)nxt((size_t)N * 4);
  int*   row_ptr = (int*)nxt((size_t)(N + 1) * 4);
  int*   col     = (int*)nxt((size_t)E * 4);
  float* dinv    = (float*)nxt((size_t)N * 4);
  float* bufA    = (float*)nxt((size_t)N * NHID * 4);
  float* bufB    = (float*)nxt((size_t)N * NHID * 4);
  unsigned short* Wt1 = (unsigned short*)nxt((size_t)NHID * NFEAT * 2);
  unsigned short* Wt2 = (unsigned short*)nxt((size_t)NHID * NHID * 2);
  unsigned short* Wt3 = (unsigned short*)nxt((size_t)NCLS * NHID * 2);
  (void)ws_size; (void)n_in; (void)out_size;

  // --- CSR + norm setup ---
  zero_int_kernel<<<(N + 255) / 256, 256, 0, stream>>>(cnt, N);
  count_kernel<<<(E + 255) / 256, 256, 0, stream>>>(dst, cnt, E);
  dinv_kernel<<<(N + 255) / 256, 256, 0, stream>>>(cnt, dinv, N);
  scan_kernel<<<1, 1024, 0, stream>>>(cnt, row_ptr, pos, N, E);
  fill_kernel<<<(E + 255) / 256, 256, 0, stream>>>(src, dst, pos, col, E);

  // --- weight transpose+cast prepass ---
  wcast_kernel<<<(NHID * NFEAT + 255) / 256, 256, 0, stream>>>(W1, Wt1, NFEAT, NHID);
  wcast_kernel<<<(NHID * NHID + 255) / 256, 256, 0, stream>>>(W2, Wt2, NHID, NHID);
  wcast_kernel<<<(NCLS * NHID + 255) / 256, 256, 0, stream>>>(W3, Wt3, NHID, NCLS);

  const int gblocks = (N + 63) / 64;

  // --- layer 1 ---
  mfma_gemm_kernel<128><<<gblocks, 256, 0, stream>>>(x, Wt1, bufA, N, NFEAT);
  agg_kernel<128, 1><<<(N + 7) / 8, 256, 0, stream>>>(bufA, row_ptr, col, dinv, b1, bufB, N);

  // --- layer 2 ---
  mfma_gemm_kernel<128><<<gblocks, 256, 0, stream>>>(bufB, Wt2, bufA, N, NHID);
  agg_kernel<128, 1><<<(N + 7) / 8, 256, 0, stream>>>(bufA, row_ptr, col, dinv, b2, bufB, N);

  // --- layer 3 ---
  mfma_gemm_kernel<64><<<gblocks, 256, 0, stream>>>(bufB, Wt3, bufA, N, NHID);
  agg_kernel<64, 0><<<(N + 15) / 16, 256, 0, stream>>>(bufA, row_ptr, col, dinv, b3, bufB, N);
  logsoftmax_kernel<<<(N + 3) / 4, 256, 0, stream>>>(bufB, out, N);
}

// Round 3
// 264.083 us; speedup vs baseline: 2.8322x; 1.6081x over previous
//
#include <hip/hip_runtime.h>
#include <math.h>

// ---------------------------------------------------------------------------
// GCN 3-layer on MI355X.
//   h = relu(Agg(x@W1)+b1); h = relu(Agg(h@W2)+b2); out = log_softmax(Agg(h@W3)+b3)
// GEMMs: bf16 MFMA 16x16x32, f32 accumulate, epilogue writes bf16 h-buffers.
// Agg: CSR built per call; atomic-free per-node gather of bf16 rows
// (ushort8 / 16B per lane), f32 accumulate, f32 output.
// Scan: 3-kernel parallel scan (was a 109 us single-block serial scan).
// ---------------------------------------------------------------------------

#define NFEAT 512
#define NHID  128
#define NCLS  64

typedef __attribute__((ext_vector_type(8))) short bf16x8;
typedef __attribute__((ext_vector_type(8))) unsigned short u16x8;
typedef __attribute__((ext_vector_type(4))) float f32x4;

__device__ __forceinline__ unsigned short f2bf(float f) {
  unsigned u = __builtin_bit_cast(unsigned, f);
  unsigned r = (u + 0x7FFFu + ((u >> 16) & 1u)) >> 16;
  return (unsigned short)r;
}
__device__ __forceinline__ float bf2f(unsigned short u) {
  return __builtin_bit_cast(float, (unsigned)u << 16);
}

// ------------------------------ CSR setup ----------------------------------
__global__ void zero_int_kernel(int* __restrict__ p, int n) {
  int i = blockIdx.x * 256 + threadIdx.x;
  if (i < n) p[i] = 0;
}

__global__ void count_kernel(const int* __restrict__ dst, int* __restrict__ cnt, int E) {
  int e = blockIdx.x * 256 + threadIdx.x;
  if (e < E) atomicAdd(&cnt[dst[e]], 1);
}

__global__ void dinv_kernel(const int* __restrict__ cnt, float* __restrict__ dinv, int N) {
  int i = blockIdx.x * 256 + threadIdx.x;
  if (i < N) dinv[i] = rsqrtf((float)(cnt[i] + 1));
}

// --- parallel scan: (1) per-block sums, (2) scan of block sums, (3) final ---
__global__ void scan_partials_kernel(const int* __restrict__ cnt, int* __restrict__ bsum, int N) {
  int i = blockIdx.x * 256 + threadIdx.x;
  int v = (i < N) ? cnt[i] : 0;
#pragma unroll
  for (int off = 32; off > 0; off >>= 1) v += __shfl_xor(v, off);
  __shared__ int ws[4];
  if ((threadIdx.x & 63) == 0) ws[threadIdx.x >> 6] = v;
  __syncthreads();
  if (threadIdx.x == 0) bsum[blockIdx.x] = ws[0] + ws[1] + ws[2] + ws[3];
}

__global__ void scan_bsums_kernel(const int* __restrict__ bsum, int* __restrict__ boff, int B) {
  __shared__ int sh[256];
  int t = threadIdx.x;
  int chunk = (B + 255) / 256;
  int beg = t * chunk;
  int end = min(beg + chunk, B);
  int s = 0;
  for (int i = beg; i < end; ++i) s += bsum[i];
  sh[t] = s;
  __syncthreads();
  for (int off = 1; off < 256; off <<= 1) {
    int u = (t >= off) ? sh[t - off] : 0;
    __syncthreads();
    sh[t] += u;
    __syncthreads();
  }
  int run = sh[t] - s;  // exclusive prefix of this thread's chunk
  for (int i = beg; i < end; ++i) {
    boff[i] = run;
    run += bsum[i];
  }
}

__global__ void scan_final_kernel(const int* __restrict__ cnt, const int* __restrict__ boff,
                                  int* __restrict__ row_ptr, int* __restrict__ pos,
                                  int N, int E) {
  __shared__ int sh[256];
  int t = threadIdx.x;
  int i = blockIdx.x * 256 + t;
  int v = (i < N) ? cnt[i] : 0;
  sh[t] = v;
  __syncthreads();
  for (int off = 1; off < 256; off <<= 1) {
    int u = (t >= off) ? sh[t - off] : 0;
    __syncthreads();
    sh[t] += u;
    __syncthreads();
  }
  int excl = sh[t] - v + boff[blockIdx.x];
  if (i < N) {
    row_ptr[i] = excl;
    pos[i] = excl;
  }
  if (i == N - 1) row_ptr[N] = E;
}

__global__ void fill_kernel(const int* __restrict__ src, const int* __restrict__ dst,
                            int* __restrict__ pos, int* __restrict__ col, int E) {
  int e = blockIdx.x * 256 + threadIdx.x;
  if (e < E) {
    int p = atomicAdd(&pos[dst[e]], 1);
    col[p] = src[e];
  }
}

// --------------------- W transpose + cast prepass --------------------------
// W [K,N] f32 row-major  ->  Wt [N,K] bf16 row-major
__global__ void wcast_kernel(const float* __restrict__ W, unsigned short* __restrict__ Wt,
                             int K, int N) {
  int idx = blockIdx.x * 256 + threadIdx.x;
  if (idx >= N * K) return;
  int n = idx / K;
  int k = idx - n * K;
  Wt[idx] = f2bf(W[(size_t)k * N + n]);
}

// --------------------------- bf16 MFMA GEMM --------------------------------
// C[M,BN](bf16) = A[M,K](f32, cast inline) @ Wt[BN,K](bf16, pre-transposed)
// BM=64, BK=64, 4 waves (2x2), wave tile 32 x BN/2.
template <int BN>
__global__ void mfma_gemm_kernel(const float* __restrict__ A,
                                 const unsigned short* __restrict__ Wt,
                                 unsigned short* __restrict__ C, int M, int K) {
  constexpr int BM = 64, BK = 64;
  constexpr int NF = BN / 32;  // 16-wide n-frags per wave
  __shared__ unsigned short Al[BM * BK];  // [row][k], XOR-swizzled
  __shared__ unsigned short Bl[BN * BK];  // [n][k],  XOR-swizzled
  const int tid = threadIdx.x;
  const int lane = tid & 63;
  const int wave = tid >> 6;
  const int wm = wave >> 1, wn = wave & 1;
  const int block_row = blockIdx.x * BM;

  f32x4 acc[2][NF];
#pragma unroll
  for (int i = 0; i < 2; ++i)
#pragma unroll
    for (int j = 0; j < NF; ++j) acc[i][j] = (f32x4){0.f, 0.f, 0.f, 0.f};

  for (int k0 = 0; k0 < K; k0 += BK) {
    // ---- stage A (f32 -> bf16, swizzled) ----
    {
      const int r = tid >> 2;            // 64 rows, 4 threads each
      const int c0 = (tid & 3) * 16;     // 16 elems per thread
      const int grow = block_row + r;
      float4 v[4];
      if (grow < M) {
        const float4* p = reinterpret_cast<const float4*>(&A[(size_t)grow * K + k0 + c0]);
        v[0] = p[0]; v[1] = p[1]; v[2] = p[2]; v[3] = p[3];
      } else {
        v[0] = v[1] = v[2] = v[3] = make_float4(0.f, 0.f, 0.f, 0.f);
      }
      unsigned short t[16];
#pragma unroll
      for (int q = 0; q < 4; ++q) {
        t[q * 4 + 0] = f2bf(v[q].x); t[q * 4 + 1] = f2bf(v[q].y);
        t[q * 4 + 2] = f2bf(v[q].z); t[q * 4 + 3] = f2bf(v[q].w);
      }
#pragma unroll
      for (int h = 0; h < 2; ++h) {
        int c = c0 + h * 8;
        int byte = r * 128 + c * 2;
        byte ^= (r & 7) << 4;
        u16x8 pk;
#pragma unroll
        for (int q = 0; q < 8; ++q) pk[q] = t[h * 8 + q];
        *reinterpret_cast<u16x8*>(reinterpret_cast<char*>(Al) + byte) = pk;
      }
    }
    // ---- stage B (bf16 copy, swizzled) ----
    {
      constexpr int NVEC = BN * BK / 8;  // u16x8 vectors total
#pragma unroll
      for (int l = 0; l < NVEC / 256; ++l) {
        int vidx = tid + l * 256;
        int n = vidx >> 3;                // BK/8 = 8 vecs per row
        int kc = (vidx & 7) * 8;
        u16x8 pk = *reinterpret_cast<const u16x8*>(&Wt[(size_t)n * K + k0 + kc]);
        int byte = n * 128 + kc * 2;
        byte ^= (n & 7) << 4;
        *reinterpret_cast<u16x8*>(reinterpret_cast<char*>(Bl) + byte) = pk;
      }
    }
    __syncthreads();
    // ---- compute ----
#pragma unroll
    for (int kk = 0; kk < 2; ++kk) {
      const int kb = kk * 32 + (lane >> 4) * 8;
      bf16x8 af[2], bfr[NF];
#pragma unroll
      for (int mf = 0; mf < 2; ++mf) {
        int r = wm * 32 + mf * 16 + (lane & 15);
        int byte = r * 128 + kb * 2;
        byte ^= (r & 7) << 4;
        af[mf] = *reinterpret_cast<bf16x8*>(reinterpret_cast<char*>(Al) + byte);
      }
#pragma unroll
      for (int nf = 0; nf < NF; ++nf) {
        int n = wn * (BN / 2) + nf * 16 + (lane & 15);
        int byte = n * 128 + kb * 2;
        byte ^= (n & 7) << 4;
        bfr[nf] = *reinterpret_cast<bf16x8*>(reinterpret_cast<char*>(Bl) + byte);
      }
#pragma unroll
      for (int mf = 0; mf < 2; ++mf)
#pragma unroll
        for (int nf = 0; nf < NF; ++nf)
          acc[mf][nf] = __builtin_amdgcn_mfma_f32_16x16x32_bf16(af[mf], bfr[nf], acc[mf][nf], 0, 0, 0);
    }
    __syncthreads();
  }
  // ---- epilogue: bf16 store ----
#pragma unroll
  for (int mf = 0; mf < 2; ++mf) {
#pragma unroll
    for (int nf = 0; nf < NF; ++nf) {
#pragma unroll
      for (int r = 0; r < 4; ++r) {
        int row = block_row + wm * 32 + mf * 16 + (lane >> 4) * 4 + r;
        int colc = wn * (BN / 2) + nf * 16 + (lane & 15);
        if (row < M) C[(size_t)row * BN + colc] = f2bf(acc[mf][nf][r]);
      }
    }
  }
}

// ----------------------------- aggregation ---------------------------------
// out[i] = op( sum_j H[col[j]]*dinv[col[j]]*dinv[i] + H[i]*dinv[i]^2 + bias )
// H is bf16 [N,F]; out is f32 [N,F]. Each lane owns 8 feats (u16x8 = 16B).
template <int F, int RELU>
__global__ void agg_kernel(const unsigned short* __restrict__ H,
                           const int* __restrict__ row_ptr, const int* __restrict__ col,
                           const float* __restrict__ dinv, const float* __restrict__ bias,
                           float* __restrict__ out, int N) {
  constexpr int LPN = F / 8;        // lanes per node
  constexpr int NPB = 256 / LPN;
  const int tid = threadIdx.x;
  const int li = tid % LPN;
  const int node = blockIdx.x * NPB + tid / LPN;
  if (node >= N) return;
  const float di = dinv[node];
  const u16x8* Hv = reinterpret_cast<const u16x8*>(H);
  u16x8 h0 = Hv[(size_t)node * LPN + li];
  const float w0 = di * di;
  float s[8];
#pragma unroll
  for (int q = 0; q < 8; ++q) s[q] = bf2f(h0[q]) * w0;
  const int beg = row_ptr[node];
  const int end = row_ptr[node + 1];
  int j = beg;
  for (; j + 1 < end; j += 2) {
    int sa = col[j];
    int sb = col[j + 1];
    float wa = dinv[sa] * di;
    float wb = dinv[sb] * di;
    u16x8 ha = Hv[(size_t)sa * LPN + li];
    u16x8 hb = Hv[(size_t)sb * LPN + li];
#pragma unroll
    for (int q = 0; q < 8; ++q) s[q] += bf2f(ha[q]) * wa;
#pragma unroll
    for (int q = 0; q < 8; ++q) s[q] += bf2f(hb[q]) * wb;
  }
  if (j < end) {
    int sa = col[j];
    float wa = dinv[sa] * di;
    u16x8 ha = Hv[(size_t)sa * LPN + li];
#pragma unroll
    for (int q = 0; q < 8; ++q) s[q] += bf2f(ha[q]) * wa;
  }
  const float4* bv = reinterpret_cast<const float4*>(bias) + li * 2;
  float4 b0 = bv[0], b1 = bv[1];
  s[0] += b0.x; s[1] += b0.y; s[2] += b0.z; s[3] += b0.w;
  s[4] += b1.x; s[5] += b1.y; s[6] += b1.z; s[7] += b1.w;
  if (RELU) {
#pragma unroll
    for (int q = 0; q < 8; ++q) s[q] = fmaxf(s[q], 0.f);
  }
  float4* ov = reinterpret_cast<float4*>(out) + (size_t)node * LPN * 2 + li * 2;
  ov[0] = make_float4(s[0], s[1], s[2], s[3]);
  ov[1] = make_float4(s[4], s[5], s[6], s[7]);
}

__global__ void logsoftmax_kernel(const float* __restrict__ H, float* __restrict__ out, int N) {
  const int lane = threadIdx.x & 63;
  const int row = blockIdx.x * 4 + (threadIdx.x >> 6);
  if (row >= N) return;
  float v = H[(size_t)row * NCLS + lane];
  float m = v;
#pragma unroll
  for (int off = 32; off > 0; off >>= 1) m = fmaxf(m, __shfl_xor(m, off));
  float e = expf(v - m);
  float ssum = e;
#pragma unroll
  for (int off = 32; off > 0; off >>= 1) ssum += __shfl_xor(ssum, off);
  out[(size_t)row * NCLS + lane] = (v - m) - logf(ssum);
}

// ---------------------------------------------------------------------------
extern "C" void kernel_launch(void* const* d_in, const int* in_sizes, int n_in,
                              void* d_out, int out_size, void* d_ws, size_t ws_size,
                              hipStream_t stream) {
  const float* x  = (const float*)d_in[0];
  const int*   ei = (const int*)d_in[1];
  const float* W1 = (const float*)d_in[2];
  const float* b1 = (const float*)d_in[3];
  const float* W2 = (const float*)d_in[4];
  const float* b2 = (const float*)d_in[5];
  const float* W3 = (const float*)d_in[6];
  const float* b3 = (const float*)d_in[7];
  float* out = (float*)d_out;

  const int N = in_sizes[0] / NFEAT;  // 50000
  const int E = in_sizes[1] / 2;      // 800000
  const int* src = ei;
  const int* dst = ei + E;

  char* ws = (char*)d_ws;
  size_t off = 0;
  auto nxt = [&](size_t bytes) -> void* {
    void* p = ws + off;
    off += (bytes + 255) & ~(size_t)255;
    return p;
  };
  const int NB = (N + 255) / 256;  // scan blocks
  int*   cnt     = (int*)nxt((size_t)N * 4);
  int*   pos     = (int*)nxt((size_t)N * 4);
  int*   row_ptr = (int*)nxt((size_t)(N + 1) * 4);
  int*   col     = (int*)nxt((size_t)E * 4);
  float* dinv    = (float*)nxt((size_t)N * 4);
  int*   bsum    = (int*)nxt((size_t)NB * 4);
  int*   boff    = (int*)nxt((size_t)NB * 4);
  unsigned short* zbuf = (unsigned short*)nxt((size_t)N * NHID * 2);  // GEMM out (bf16)
  float* hbuf    = (float*)nxt((size_t)N * NHID * 4);                 // agg out (f32)
  unsigned short* Wt1 = (unsigned short*)nxt((size_t)NHID * NFEAT * 2);
  unsigned short* Wt2 = (unsigned short*)nxt((size_t)NHID * NHID * 2);
  unsigned short* Wt3 = (unsigned short*)nxt((size_t)NCLS * NHID * 2);
  (void)ws_size; (void)n_in; (void)out_size;

  // --- CSR + norm setup ---
  zero_int_kernel<<<NB, 256, 0, stream>>>(cnt, N);
  count_kernel<<<(E + 255) / 256, 256, 0, stream>>>(dst, cnt, E);
  dinv_kernel<<<NB, 256, 0, stream>>>(cnt, dinv, N);
  scan_partials_kernel<<<NB, 256, 0, stream>>>(cnt, bsum, N);
  scan_bsums_kernel<<<1, 256, 0, stream>>>(bsum, boff, NB);
  scan_final_kernel<<<NB, 256, 0, stream>>>(cnt, boff, row_ptr, pos, N, E);
  fill_kernel<<<(E + 255) / 256, 256, 0, stream>>>(src, dst, pos, col, E);

  // --- weight transpose+cast prepass ---
  wcast_kernel<<<(NHID * NFEAT + 255) / 256, 256, 0, stream>>>(W1, Wt1, NFEAT, NHID);
  wcast_kernel<<<(NHID * NHID + 255) / 256, 256, 0, stream>>>(W2, Wt2, NHID, NHID);
  wcast_kernel<<<(NCLS * NHID + 255) / 256, 256, 0, stream>>>(W3, Wt3, NHID, NCLS);

  const int gblocks = (N + 63) / 64;

  // --- layer 1 ---
  mfma_gemm_kernel<128><<<gblocks, 256, 0, stream>>>(x, Wt1, zbuf, N, NFEAT);
  agg_kernel<128, 1><<<(N + 15) / 16, 256, 0, stream>>>(zbuf, row_ptr, col, dinv, b1, hbuf, N);

  // --- layer 2 ---
  mfma_gemm_kernel<128><<<gblocks, 256, 0, stream>>>(hbuf, Wt2, zbuf, N, NHID);
  agg_kernel<128, 1><<<(N + 15) / 16, 256, 0, stream>>>(zbuf, row_ptr, col, dinv, b2, hbuf, N);

  // --- layer 3 ---
  mfma_gemm_kernel<64><<<gblocks, 256, 0, stream>>>(hbuf, Wt3, zbuf, N, NHID);
  agg_kernel<64, 0><<<(N + 31) / 32, 256, 0, stream>>>(zbuf, row_ptr, col, dinv, b3, hbuf, N);
  logsoftmax_kernel<<<(N + 3) / 4, 256, 0, stream>>>(hbuf, out, N);
}

// Round 4
// 259.496 us; speedup vs baseline: 2.8822x; 1.0177x over previous
//
#include <hip/hip_runtime.h>
#include <math.h>

// ---------------------------------------------------------------------------
// GCN 3-layer on MI355X.
// GEMMs: bf16 MFMA 16x16x32, f32 accumulate, bf16 outputs. A input f32
// (layer1: x) or bf16 (layers 2/3: agg output).
// Agg: CSR per call; one WAVE per node, edge-slots across the wave (no
// divergence), 4-wide unrolled gathers, per-edge weights precomputed in fill,
// cross-slot shfl reduce. bf16 output for layers 1/2, f32 for layer 3.
// ---------------------------------------------------------------------------

#define NFEAT 512
#define NHID  128
#define NCLS  64

typedef __attribute__((ext_vector_type(8))) short bf16x8;
typedef __attribute__((ext_vector_type(8))) unsigned short u16x8;
typedef __attribute__((ext_vector_type(4))) float f32x4;

__device__ __forceinline__ unsigned short f2bf(float f) {
  unsigned u = __builtin_bit_cast(unsigned, f);
  unsigned r = (u + 0x7FFFu + ((u >> 16) & 1u)) >> 16;
  return (unsigned short)r;
}
__device__ __forceinline__ float bf2f(unsigned short u) {
  return __builtin_bit_cast(float, (unsigned)u << 16);
}

// ------------------------------ CSR setup ----------------------------------
__global__ void zero_int_kernel(int* __restrict__ p, int n) {
  int i = blockIdx.x * 256 + threadIdx.x;
  if (i < n) p[i] = 0;
}

__global__ void count_kernel(const int* __restrict__ dst, int* __restrict__ cnt, int E) {
  int e = blockIdx.x * 256 + threadIdx.x;
  if (e < E) atomicAdd(&cnt[dst[e]], 1);
}

__global__ void dinv_kernel(const int* __restrict__ cnt, float* __restrict__ dinv, int N) {
  int i = blockIdx.x * 256 + threadIdx.x;
  if (i < N) dinv[i] = rsqrtf((float)(cnt[i] + 1));
}

__global__ void scan_partials_kernel(const int* __restrict__ cnt, int* __restrict__ bsum, int N) {
  int i = blockIdx.x * 256 + threadIdx.x;
  int v = (i < N) ? cnt[i] : 0;
#pragma unroll
  for (int off = 32; off > 0; off >>= 1) v += __shfl_xor(v, off);
  __shared__ int ws[4];
  if ((threadIdx.x & 63) == 0) ws[threadIdx.x >> 6] = v;
  __syncthreads();
  if (threadIdx.x == 0) bsum[blockIdx.x] = ws[0] + ws[1] + ws[2] + ws[3];
}

__global__ void scan_bsums_kernel(const int* __restrict__ bsum, int* __restrict__ boff, int B) {
  __shared__ int sh[256];
  int t = threadIdx.x;
  int chunk = (B + 255) / 256;
  int beg = t * chunk;
  int end = min(beg + chunk, B);
  int s = 0;
  for (int i = beg; i < end; ++i) s += bsum[i];
  sh[t] = s;
  __syncthreads();
  for (int off = 1; off < 256; off <<= 1) {
    int u = (t >= off) ? sh[t - off] : 0;
    __syncthreads();
    sh[t] += u;
    __syncthreads();
  }
  int run = sh[t] - s;
  for (int i = beg; i < end; ++i) {
    boff[i] = run;
    run += bsum[i];
  }
}

__global__ void scan_final_kernel(const int* __restrict__ cnt, const int* __restrict__ boff,
                                  int* __restrict__ row_ptr, int* __restrict__ pos,
                                  int N, int E) {
  __shared__ int sh[256];
  int t = threadIdx.x;
  int i = blockIdx.x * 256 + t;
  int v = (i < N) ? cnt[i] : 0;
  sh[t] = v;
  __syncthreads();
  for (int off = 1; off < 256; off <<= 1) {
    int u = (t >= off) ? sh[t - off] : 0;
    __syncthreads();
    sh[t] += u;
    __syncthreads();
  }
  int excl = sh[t] - v + boff[blockIdx.x];
  if (i < N) {
    row_ptr[i] = excl;
    pos[i] = excl;
  }
  if (i == N - 1) row_ptr[N] = E;
}

// fill CSR columns + per-edge source weight (dinv[src]) in one pass
__global__ void fill_kernel(const int* __restrict__ src, const int* __restrict__ dst,
                            int* __restrict__ pos, int* __restrict__ col,
                            float* __restrict__ wcol, const float* __restrict__ dinv, int E) {
  int e = blockIdx.x * 256 + threadIdx.x;
  if (e < E) {
    int s = src[e];
    int p = atomicAdd(&pos[dst[e]], 1);
    col[p] = s;
    wcol[p] = dinv[s];
  }
}

// --------------------- W transpose + cast prepass --------------------------
__global__ void wcast_kernel(const float* __restrict__ W, unsigned short* __restrict__ Wt,
                             int K, int N) {
  int idx = blockIdx.x * 256 + threadIdx.x;
  if (idx >= N * K) return;
  int n = idx / K;
  int k = idx - n * K;
  Wt[idx] = f2bf(W[(size_t)k * N + n]);
}

// --------------------------- bf16 MFMA GEMM --------------------------------
// C[M,BN](bf16) = A[M,K] @ Wt[BN,K](bf16). A is f32 (A_BF16=0) or bf16 (=1).
template <int BN, bool A_BF16>
__global__ void mfma_gemm_kernel(const void* __restrict__ Av,
                                 const unsigned short* __restrict__ Wt,
                                 unsigned short* __restrict__ C, int M, int K) {
  constexpr int BM = 64, BK = 64;
  constexpr int NF = BN / 32;
  __shared__ unsigned short Al[BM * BK];
  __shared__ unsigned short Bl[BN * BK];
  const int tid = threadIdx.x;
  const int lane = tid & 63;
  const int wave = tid >> 6;
  const int wm = wave >> 1, wn = wave & 1;
  const int block_row = blockIdx.x * BM;

  f32x4 acc[2][NF];
#pragma unroll
  for (int i = 0; i < 2; ++i)
#pragma unroll
    for (int j = 0; j < NF; ++j) acc[i][j] = (f32x4){0.f, 0.f, 0.f, 0.f};

  for (int k0 = 0; k0 < K; k0 += BK) {
    if constexpr (!A_BF16) {
      const float* A = (const float*)Av;
      const int r = tid >> 2;
      const int c0 = (tid & 3) * 16;
      const int grow = block_row + r;
      float4 v[4];
      if (grow < M) {
        const float4* p = reinterpret_cast<const float4*>(&A[(size_t)grow * K + k0 + c0]);
        v[0] = p[0]; v[1] = p[1]; v[2] = p[2]; v[3] = p[3];
      } else {
        v[0] = v[1] = v[2] = v[3] = make_float4(0.f, 0.f, 0.f, 0.f);
      }
      unsigned short t[16];
#pragma unroll
      for (int q = 0; q < 4; ++q) {
        t[q * 4 + 0] = f2bf(v[q].x); t[q * 4 + 1] = f2bf(v[q].y);
        t[q * 4 + 2] = f2bf(v[q].z); t[q * 4 + 3] = f2bf(v[q].w);
      }
#pragma unroll
      for (int h = 0; h < 2; ++h) {
        int c = c0 + h * 8;
        int byte = r * 128 + c * 2;
        byte ^= (r & 7) << 4;
        u16x8 pk;
#pragma unroll
        for (int q = 0; q < 8; ++q) pk[q] = t[h * 8 + q];
        *reinterpret_cast<u16x8*>(reinterpret_cast<char*>(Al) + byte) = pk;
      }
    } else {
      const unsigned short* A = (const unsigned short*)Av;
#pragma unroll
      for (int l = 0; l < 2; ++l) {
        int vidx = tid + l * 256;
        int r = vidx >> 3;
        int kc = (vidx & 7) * 8;
        int grow = block_row + r;
        u16x8 pk = (u16x8){0, 0, 0, 0, 0, 0, 0, 0};
        if (grow < M) pk = *reinterpret_cast<const u16x8*>(&A[(size_t)grow * K + k0 + kc]);
        int byte = r * 128 + kc * 2;
        byte ^= (r & 7) << 4;
        *reinterpret_cast<u16x8*>(reinterpret_cast<char*>(Al) + byte) = pk;
      }
    }
    {
      constexpr int NVEC = BN * BK / 8;
#pragma unroll
      for (int l = 0; l < NVEC / 256; ++l) {
        int vidx = tid + l * 256;
        int n = vidx >> 3;
        int kc = (vidx & 7) * 8;
        u16x8 pk = *reinterpret_cast<const u16x8*>(&Wt[(size_t)n * K + k0 + kc]);
        int byte = n * 128 + kc * 2;
        byte ^= (n & 7) << 4;
        *reinterpret_cast<u16x8*>(reinterpret_cast<char*>(Bl) + byte) = pk;
      }
    }
    __syncthreads();
#pragma unroll
    for (int kk = 0; kk < 2; ++kk) {
      const int kb = kk * 32 + (lane >> 4) * 8;
      bf16x8 af[2], bfr[NF];
#pragma unroll
      for (int mf = 0; mf < 2; ++mf) {
        int r = wm * 32 + mf * 16 + (lane & 15);
        int byte = r * 128 + kb * 2;
        byte ^= (r & 7) << 4;
        af[mf] = *reinterpret_cast<bf16x8*>(reinterpret_cast<char*>(Al) + byte);
      }
#pragma unroll
      for (int nf = 0; nf < NF; ++nf) {
        int n = wn * (BN / 2) + nf * 16 + (lane & 15);
        int byte = n * 128 + kb * 2;
        byte ^= (n & 7) << 4;
        bfr[nf] = *reinterpret_cast<bf16x8*>(reinterpret_cast<char*>(Bl) + byte);
      }
#pragma unroll
      for (int mf = 0; mf < 2; ++mf)
#pragma unroll
        for (int nf = 0; nf < NF; ++nf)
          acc[mf][nf] = __builtin_amdgcn_mfma_f32_16x16x32_bf16(af[mf], bfr[nf], acc[mf][nf], 0, 0, 0);
    }
    __syncthreads();
  }
#pragma unroll
  for (int mf = 0; mf < 2; ++mf) {
#pragma unroll
    for (int nf = 0; nf < NF; ++nf) {
#pragma unroll
      for (int r = 0; r < 4; ++r) {
        int row = block_row + wm * 32 + mf * 16 + (lane >> 4) * 4 + r;
        int colc = wn * (BN / 2) + nf * 16 + (lane & 15);
        if (row < M) C[(size_t)row * BN + colc] = f2bf(acc[mf][nf][r]);
      }
    }
  }
}

// ----------------------------- aggregation ---------------------------------
// One wave per node. LPN = F/8 lanes per row chunk; SLOTS = 64/LPN edges in
// parallel per iteration, 4-wide unrolled. Cross-slot shfl_xor reduce.
// out[i] = op( sum_j H[col[j]]*wcol[j]*di + H[i]*di^2 + bias )
template <int F, int RELU, bool OUT_BF16>
__global__ void agg_kernel(const unsigned short* __restrict__ H,
                           const int* __restrict__ row_ptr, const int* __restrict__ col,
                           const float* __restrict__ wcol, const float* __restrict__ dinv,
                           const float* __restrict__ bias, void* __restrict__ out, int N) {
  constexpr int LPN = F / 8;
  constexpr int SLOTS = 64 / LPN;
  const int tid = threadIdx.x;
  const int lane = tid & 63;
  const int li = lane & (LPN - 1);
  const int slot = lane / LPN;
  const int node = blockIdx.x * 4 + (tid >> 6);
  if (node >= N) return;
  const float di = dinv[node];
  const u16x8* Hv = reinterpret_cast<const u16x8*>(H);
  // self-row: issue early (used after reduction)
  u16x8 h0 = Hv[(size_t)node * LPN + li];

  float s[8];
#pragma unroll
  for (int q = 0; q < 8; ++q) s[q] = 0.f;

  const int beg = row_ptr[node];
  const int end = row_ptr[node + 1];
  int j = beg + slot;
  for (; j + 3 * SLOTS < end; j += 4 * SLOTS) {
    int i0 = col[j], i1 = col[j + SLOTS], i2 = col[j + 2 * SLOTS], i3 = col[j + 3 * SLOTS];
    float w0 = wcol[j] * di, w1 = wcol[j + SLOTS] * di;
    float w2 = wcol[j + 2 * SLOTS] * di, w3 = wcol[j + 3 * SLOTS] * di;
    u16x8 r0 = Hv[(size_t)i0 * LPN + li];
    u16x8 r1 = Hv[(size_t)i1 * LPN + li];
    u16x8 r2 = Hv[(size_t)i2 * LPN + li];
    u16x8 r3 = Hv[(size_t)i3 * LPN + li];
#pragma unroll
    for (int q = 0; q < 8; ++q)
      s[q] += bf2f(r0[q]) * w0 + bf2f(r1[q]) * w1 + bf2f(r2[q]) * w2 + bf2f(r3[q]) * w3;
  }
  if (j + SLOTS < end) {
    int i0 = col[j], i1 = col[j + SLOTS];
    float w0 = wcol[j] * di, w1 = wcol[j + SLOTS] * di;
    u16x8 r0 = Hv[(size_t)i0 * LPN + li];
    u16x8 r1 = Hv[(size_t)i1 * LPN + li];
#pragma unroll
    for (int q = 0; q < 8; ++q) s[q] += bf2f(r0[q]) * w0 + bf2f(r1[q]) * w1;
    j += 2 * SLOTS;
  }
  if (j < end) {
    int i0 = col[j];
    float w0 = wcol[j] * di;
    u16x8 r0 = Hv[(size_t)i0 * LPN + li];
#pragma unroll
    for (int q = 0; q < 8; ++q) s[q] += bf2f(r0[q]) * w0;
  }
  // reduce across slots
#pragma unroll
  for (int off = LPN; off < 64; off <<= 1) {
#pragma unroll
    for (int q = 0; q < 8; ++q) s[q] += __shfl_xor(s[q], off);
  }
  if (slot == 0) {
    const float w0 = di * di;
    const float4* bv = reinterpret_cast<const float4*>(bias) + li * 2;
    float4 b0 = bv[0], b1 = bv[1];
    float sv[8];
#pragma unroll
    for (int q = 0; q < 8; ++q) sv[q] = s[q] + bf2f(h0[q]) * w0;
    sv[0] += b0.x; sv[1] += b0.y; sv[2] += b0.z; sv[3] += b0.w;
    sv[4] += b1.x; sv[5] += b1.y; sv[6] += b1.z; sv[7] += b1.w;
    if (RELU) {
#pragma unroll
      for (int q = 0; q < 8; ++q) sv[q] = fmaxf(sv[q], 0.f);
    }
    if constexpr (OUT_BF16) {
      u16x8 pk;
#pragma unroll
      for (int q = 0; q < 8; ++q) pk[q] = f2bf(sv[q]);
      reinterpret_cast<u16x8*>(out)[(size_t)node * LPN + li] = pk;
    } else {
      float4* ov = reinterpret_cast<float4*>(out) + (size_t)node * LPN * 2 + li * 2;
      ov[0] = make_float4(sv[0], sv[1], sv[2], sv[3]);
      ov[1] = make_float4(sv[4], sv[5], sv[6], sv[7]);
    }
  }
}

__global__ void logsoftmax_kernel(const float* __restrict__ H, float* __restrict__ out, int N) {
  const int lane = threadIdx.x & 63;
  const int row = blockIdx.x * 4 + (threadIdx.x >> 6);
  if (row >= N) return;
  float v = H[(size_t)row * NCLS + lane];
  float m = v;
#pragma unroll
  for (int off = 32; off > 0; off >>= 1) m = fmaxf(m, __shfl_xor(m, off));
  float e = expf(v - m);
  float ssum = e;
#pragma unroll
  for (int off = 32; off > 0; off >>= 1) ssum += __shfl_xor(ssum, off);
  out[(size_t)row * NCLS + lane] = (v - m) - logf(ssum);
}

// ---------------------------------------------------------------------------
extern "C" void kernel_launch(void* const* d_in, const int* in_sizes, int n_in,
                              void* d_out, int out_size, void* d_ws, size_t ws_size,
                              hipStream_t stream) {
  const float* x  = (const float*)d_in[0];
  const int*   ei = (const int*)d_in[1];
  const float* W1 = (const float*)d_in[2];
  const float* b1 = (const float*)d_in[3];
  const float* W2 = (const float*)d_in[4];
  const float* b2 = (const float*)d_in[5];
  const float* W3 = (const float*)d_in[6];
  const float* b3 = (const float*)d_in[7];
  float* out = (float*)d_out;

  const int N = in_sizes[0] / NFEAT;  // 50000
  const int E = in_sizes[1] / 2;      // 800000
  const int* src = ei;
  const int* dst = ei + E;

  char* ws = (char*)d_ws;
  size_t off = 0;
  auto nxt = [&](size_t bytes) -> void* {
    void* p = ws + off;
    off += (bytes + 255) & ~(size_t)255;
    return p;
  };
  const int NB = (N + 255) / 256;
  int*   cnt     = (int*)nxt((size_t)N * 4);
  int*   pos     = (int*)nxt((size_t)N * 4);
  int*   row_ptr = (int*)nxt((size_t)(N + 1) * 4);
  int*   col     = (int*)nxt((size_t)E * 4);
  float* wcol    = (float*)nxt((size_t)E * 4);
  float* dinv    = (float*)nxt((size_t)N * 4);
  int*   bsum    = (int*)nxt((size_t)NB * 4);
  int*   boff    = (int*)nxt((size_t)NB * 4);
  unsigned short* zbuf = (unsigned short*)nxt((size_t)N * NHID * 2);  // GEMM out (bf16)
  unsigned short* hb16 = (unsigned short*)nxt((size_t)N * NHID * 2);  // agg out (bf16)
  float* hbuf    = (float*)nxt((size_t)N * NCLS * 4);                 // agg3 out (f32)
  unsigned short* Wt1 = (unsigned short*)nxt((size_t)NHID * NFEAT * 2);
  unsigned short* Wt2 = (unsigned short*)nxt((size_t)NHID * NHID * 2);
  unsigned short* Wt3 = (unsigned short*)nxt((size_t)NCLS * NHID * 2);
  (void)ws_size; (void)n_in; (void)out_size;

  // --- CSR + norm setup ---
  zero_int_kernel<<<NB, 256, 0, stream>>>(cnt, N);
  count_kernel<<<(E + 255) / 256, 256, 0, stream>>>(dst, cnt, E);
  dinv_kernel<<<NB, 256, 0, stream>>>(cnt, dinv, N);
  scan_partials_kernel<<<NB, 256, 0, stream>>>(cnt, bsum, N);
  scan_bsums_kernel<<<1, 256, 0, stream>>>(bsum, boff, NB);
  scan_final_kernel<<<NB, 256, 0, stream>>>(cnt, boff, row_ptr, pos, N, E);
  fill_kernel<<<(E + 255) / 256, 256, 0, stream>>>(src, dst, pos, col, wcol, dinv, E);

  // --- weight transpose+cast prepass ---
  wcast_kernel<<<(NHID * NFEAT + 255) / 256, 256, 0, stream>>>(W1, Wt1, NFEAT, NHID);
  wcast_kernel<<<(NHID * NHID + 255) / 256, 256, 0, stream>>>(W2, Wt2, NHID, NHID);
  wcast_kernel<<<(NCLS * NHID + 255) / 256, 256, 0, stream>>>(W3, Wt3, NHID, NCLS);

  const int gblocks = (N + 63) / 64;
  const int ablocks = (N + 3) / 4;

  // --- layer 1 ---
  mfma_gemm_kernel<128, false><<<gblocks, 256, 0, stream>>>(x, Wt1, zbuf, N, NFEAT);
  agg_kernel<128, 1, true><<<ablocks, 256, 0, stream>>>(zbuf, row_ptr, col, wcol, dinv, b1, hb16, N);

  // --- layer 2 ---
  mfma_gemm_kernel<128, true><<<gblocks, 256, 0, stream>>>(hb16, Wt2, zbuf, N, NHID);
  agg_kernel<128, 1, true><<<ablocks, 256, 0, stream>>>(zbuf, row_ptr, col, wcol, dinv, b2, hb16, N);

  // --- layer 3 ---
  mfma_gemm_kernel<64, true><<<gblocks, 256, 0, stream>>>(hb16, Wt3, zbuf, N, NHID);
  agg_kernel<64, 0, false><<<ablocks, 256, 0, stream>>>(zbuf, row_ptr, col, wcol, dinv, b3, hbuf, N);
  logsoftmax_kernel<<<ablocks, 256, 0, stream>>>(hbuf, out, N);
}

// Round 5
// 224.291 us; speedup vs baseline: 3.3347x; 1.1570x over previous
//
#include <hip/hip_runtime.h>
#include <math.h>

// ---------------------------------------------------------------------------
// GCN 3-layer on MI355X.
// Key algebra: GEMM epilogue pre-scales rows by dinv -> z'[i]=z[i]*dinv[i],
// so Agg(i) = dinv[i]*(sum_j z'[col_j] + z'[i]) + b : NO per-edge weights.
// CSR built per call; fill co-scheduled with GEMM1 in one fused kernel.
// agg3 fused with log_softmax. 11 dispatches total.
// ---------------------------------------------------------------------------

#define NFEAT 512
#define NHID  128
#define NCLS  64

typedef __attribute__((ext_vector_type(8))) short bf16x8;
typedef __attribute__((ext_vector_type(8))) unsigned short u16x8;
typedef __attribute__((ext_vector_type(4))) float f32x4;

__device__ __forceinline__ unsigned short f2bf(float f) {
  unsigned u = __builtin_bit_cast(unsigned, f);
  unsigned r = (u + 0x7FFFu + ((u >> 16) & 1u)) >> 16;
  return (unsigned short)r;
}
__device__ __forceinline__ float bf2f(unsigned short u) {
  return __builtin_bit_cast(float, (unsigned)u << 16);
}

// ------------------- fused setup: zero cnt + wcast x3 ----------------------
__device__ __forceinline__ void wcast_body(const float* __restrict__ W,
                                           unsigned short* __restrict__ Wt,
                                           int K, int N, int bid) {
  int idx = bid * 256 + threadIdx.x;
  if (idx >= N * K) return;
  int n = idx / K;
  int k = idx - n * K;
  Wt[idx] = f2bf(W[(size_t)k * N + n]);
}

__global__ void setup_kernel(int* __restrict__ cnt, int NB, int N,
                             const float* __restrict__ W1, unsigned short* __restrict__ Wt1,
                             const float* __restrict__ W2, unsigned short* __restrict__ Wt2,
                             const float* __restrict__ W3, unsigned short* __restrict__ Wt3) {
  int b = blockIdx.x;
  if (b < NB) {
    int i = b * 256 + threadIdx.x;
    if (i < N) cnt[i] = 0;
    return;
  }
  b -= NB;
  if (b < 256) { wcast_body(W1, Wt1, NFEAT, NHID, b); return; }
  b -= 256;
  if (b < 64) { wcast_body(W2, Wt2, NHID, NHID, b); return; }
  b -= 64;
  wcast_body(W3, Wt3, NHID, NCLS, b);
}

__global__ void count_kernel(const int* __restrict__ dst, int* __restrict__ cnt, int E) {
  int e = blockIdx.x * 256 + threadIdx.x;
  if (e < E) atomicAdd(&cnt[dst[e]], 1);
}

// dinv + per-block partial sums in one pass
__global__ void dinv_partials_kernel(const int* __restrict__ cnt, float* __restrict__ dinv,
                                     int* __restrict__ bsum, int N) {
  int i = blockIdx.x * 256 + threadIdx.x;
  int c = (i < N) ? cnt[i] : 0;
  if (i < N) dinv[i] = rsqrtf((float)(c + 1));
  int v = c;
#pragma unroll
  for (int off = 32; off > 0; off >>= 1) v += __shfl_xor(v, off);
  __shared__ int ws[4];
  if ((threadIdx.x & 63) == 0) ws[threadIdx.x >> 6] = v;
  __syncthreads();
  if (threadIdx.x == 0) bsum[blockIdx.x] = ws[0] + ws[1] + ws[2] + ws[3];
}

__global__ void scan_bsums_kernel(const int* __restrict__ bsum, int* __restrict__ boff, int B) {
  __shared__ int sh[256];
  int t = threadIdx.x;
  int chunk = (B + 255) / 256;
  int beg = t * chunk;
  int end = min(beg + chunk, B);
  int s = 0;
  for (int i = beg; i < end; ++i) s += bsum[i];
  sh[t] = s;
  __syncthreads();
  for (int off = 1; off < 256; off <<= 1) {
    int u = (t >= off) ? sh[t - off] : 0;
    __syncthreads();
    sh[t] += u;
    __syncthreads();
  }
  int run = sh[t] - s;
  for (int i = beg; i < end; ++i) {
    boff[i] = run;
    run += bsum[i];
  }
}

__global__ void scan_final_kernel(const int* __restrict__ cnt, const int* __restrict__ boff,
                                  int* __restrict__ row_ptr, int* __restrict__ pos,
                                  int N, int E) {
  __shared__ int sh[256];
  int t = threadIdx.x;
  int i = blockIdx.x * 256 + t;
  int v = (i < N) ? cnt[i] : 0;
  sh[t] = v;
  __syncthreads();
  for (int off = 1; off < 256; off <<= 1) {
    int u = (t >= off) ? sh[t - off] : 0;
    __syncthreads();
    sh[t] += u;
    __syncthreads();
  }
  int excl = sh[t] - v + boff[blockIdx.x];
  if (i < N) {
    row_ptr[i] = excl;
    pos[i] = excl;
  }
  if (i == N - 1) row_ptr[N] = E;
}

// --------------------------- GEMM body (device) ----------------------------
// C[M,BN](bf16) = (A[M,K] @ Wt[BN,K]) * dinv[row].  A f32 or bf16.
template <int BN, bool A_BF16>
__device__ __forceinline__ void gemm_body(const void* __restrict__ Av,
                                          const unsigned short* __restrict__ Wt,
                                          const float* __restrict__ dinv,
                                          unsigned short* __restrict__ C,
                                          int M, int K, int bid) {
  constexpr int BM = 64, BK = 64;
  constexpr int NF = BN / 32;
  __shared__ unsigned short Al[BM * BK];
  __shared__ unsigned short Bl[(BN > BM ? BN : BM) * BK];
  const int tid = threadIdx.x;
  const int lane = tid & 63;
  const int wave = tid >> 6;
  const int wm = wave >> 1, wn = wave & 1;
  const int block_row = bid * BM;

  f32x4 acc[2][NF];
#pragma unroll
  for (int i = 0; i < 2; ++i)
#pragma unroll
    for (int j = 0; j < NF; ++j) acc[i][j] = (f32x4){0.f, 0.f, 0.f, 0.f};

  for (int k0 = 0; k0 < K; k0 += BK) {
    if constexpr (!A_BF16) {
      const float* A = (const float*)Av;
      const int r = tid >> 2;
      const int c0 = (tid & 3) * 16;
      const int grow = block_row + r;
      float4 v[4];
      if (grow < M) {
        const float4* p = reinterpret_cast<const float4*>(&A[(size_t)grow * K + k0 + c0]);
        v[0] = p[0]; v[1] = p[1]; v[2] = p[2]; v[3] = p[3];
      } else {
        v[0] = v[1] = v[2] = v[3] = make_float4(0.f, 0.f, 0.f, 0.f);
      }
      unsigned short t[16];
#pragma unroll
      for (int q = 0; q < 4; ++q) {
        t[q * 4 + 0] = f2bf(v[q].x); t[q * 4 + 1] = f2bf(v[q].y);
        t[q * 4 + 2] = f2bf(v[q].z); t[q * 4 + 3] = f2bf(v[q].w);
      }
#pragma unroll
      for (int h = 0; h < 2; ++h) {
        int c = c0 + h * 8;
        int byte = r * 128 + c * 2;
        byte ^= (r & 7) << 4;
        u16x8 pk;
#pragma unroll
        for (int q = 0; q < 8; ++q) pk[q] = t[h * 8 + q];
        *reinterpret_cast<u16x8*>(reinterpret_cast<char*>(Al) + byte) = pk;
      }
    } else {
      const unsigned short* A = (const unsigned short*)Av;
#pragma unroll
      for (int l = 0; l < 2; ++l) {
        int vidx = tid + l * 256;
        int r = vidx >> 3;
        int kc = (vidx & 7) * 8;
        int grow = block_row + r;
        u16x8 pk = (u16x8){0, 0, 0, 0, 0, 0, 0, 0};
        if (grow < M) pk = *reinterpret_cast<const u16x8*>(&A[(size_t)grow * K + k0 + kc]);
        int byte = r * 128 + kc * 2;
        byte ^= (r & 7) << 4;
        *reinterpret_cast<u16x8*>(reinterpret_cast<char*>(Al) + byte) = pk;
      }
    }
    {
      constexpr int NVEC = BN * BK / 8;
#pragma unroll
      for (int l = 0; l < NVEC / 256; ++l) {
        int vidx = tid + l * 256;
        int n = vidx >> 3;
        int kc = (vidx & 7) * 8;
        u16x8 pk = *reinterpret_cast<const u16x8*>(&Wt[(size_t)n * K + k0 + kc]);
        int byte = n * 128 + kc * 2;
        byte ^= (n & 7) << 4;
        *reinterpret_cast<u16x8*>(reinterpret_cast<char*>(Bl) + byte) = pk;
      }
    }
    __syncthreads();
#pragma unroll
    for (int kk = 0; kk < 2; ++kk) {
      const int kb = kk * 32 + (lane >> 4) * 8;
      bf16x8 af[2], bfr[NF];
#pragma unroll
      for (int mf = 0; mf < 2; ++mf) {
        int r = wm * 32 + mf * 16 + (lane & 15);
        int byte = r * 128 + kb * 2;
        byte ^= (r & 7) << 4;
        af[mf] = *reinterpret_cast<bf16x8*>(reinterpret_cast<char*>(Al) + byte);
      }
#pragma unroll
      for (int nf = 0; nf < NF; ++nf) {
        int n = wn * (BN / 2) + nf * 16 + (lane & 15);
        int byte = n * 128 + kb * 2;
        byte ^= (n & 7) << 4;
        bfr[nf] = *reinterpret_cast<bf16x8*>(reinterpret_cast<char*>(Bl) + byte);
      }
#pragma unroll
      for (int mf = 0; mf < 2; ++mf)
#pragma unroll
        for (int nf = 0; nf < NF; ++nf)
          acc[mf][nf] = __builtin_amdgcn_mfma_f32_16x16x32_bf16(af[mf], bfr[nf], acc[mf][nf], 0, 0, 0);
    }
    __syncthreads();
  }
#pragma unroll
  for (int mf = 0; mf < 2; ++mf) {
#pragma unroll
    for (int r = 0; r < 4; ++r) {
      int row = block_row + wm * 32 + mf * 16 + (lane >> 4) * 4 + r;
      if (row < M) {
        float dr = dinv[row];
#pragma unroll
        for (int nf = 0; nf < NF; ++nf) {
          int colc = wn * (BN / 2) + nf * 16 + (lane & 15);
          C[(size_t)row * BN + colc] = f2bf(acc[mf][nf][r] * dr);
        }
      }
    }
  }
}

template <int BN, bool A_BF16>
__global__ void mfma_gemm_kernel(const void* __restrict__ Av,
                                 const unsigned short* __restrict__ Wt,
                                 const float* __restrict__ dinv,
                                 unsigned short* __restrict__ C, int M, int K) {
  gemm_body<BN, A_BF16>(Av, Wt, dinv, C, M, K, blockIdx.x);
}

// --------------------- fused GEMM1 || CSR fill -----------------------------
__device__ __forceinline__ void fill_body(const int* __restrict__ src,
                                          const int* __restrict__ dst,
                                          int* __restrict__ pos, int* __restrict__ col,
                                          int E, int bid) {
  int e = bid * 256 + threadIdx.x;
  if (e < E) {
    int s = src[e];
    int p = atomicAdd(&pos[dst[e]], 1);
    col[p] = s;
  }
}

__global__ void gemm1_fill_kernel(const float* __restrict__ x,
                                  const unsigned short* __restrict__ Wt1,
                                  const float* __restrict__ dinv,
                                  unsigned short* __restrict__ C, int M,
                                  const int* __restrict__ src, const int* __restrict__ dst,
                                  int* __restrict__ pos, int* __restrict__ col,
                                  int E, int GB) {
  if ((int)blockIdx.x < GB) {
    gemm_body<128, false>(x, Wt1, dinv, C, M, NFEAT, blockIdx.x);
  } else {
    fill_body(src, dst, pos, col, E, blockIdx.x - GB);
  }
}

// ----------------------------- aggregation ---------------------------------
// One wave per node; H holds pre-scaled rows z'. out = (sum + self)*di + b.
template <int F, int RELU, bool OUT_BF16>
__global__ void agg_kernel(const unsigned short* __restrict__ H,
                           const int* __restrict__ row_ptr, const int* __restrict__ col,
                           const float* __restrict__ dinv, const float* __restrict__ bias,
                           void* __restrict__ out, int N) {
  constexpr int LPN = F / 8;
  constexpr int SLOTS = 64 / LPN;
  const int tid = threadIdx.x;
  const int lane = tid & 63;
  const int li = lane & (LPN - 1);
  const int slot = lane / LPN;
  const int node = blockIdx.x * 4 + (tid >> 6);
  if (node >= N) return;
  const float di = dinv[node];
  const u16x8* Hv = reinterpret_cast<const u16x8*>(H);
  u16x8 h0 = Hv[(size_t)node * LPN + li];

  float s[8];
#pragma unroll
  for (int q = 0; q < 8; ++q) s[q] = 0.f;

  const int beg = row_ptr[node];
  const int end = row_ptr[node + 1];
  int j = beg + slot;
  for (; j + 3 * SLOTS < end; j += 4 * SLOTS) {
    int i0 = col[j], i1 = col[j + SLOTS], i2 = col[j + 2 * SLOTS], i3 = col[j + 3 * SLOTS];
    u16x8 r0 = Hv[(size_t)i0 * LPN + li];
    u16x8 r1 = Hv[(size_t)i1 * LPN + li];
    u16x8 r2 = Hv[(size_t)i2 * LPN + li];
    u16x8 r3 = Hv[(size_t)i3 * LPN + li];
#pragma unroll
    for (int q = 0; q < 8; ++q)
      s[q] += (bf2f(r0[q]) + bf2f(r1[q])) + (bf2f(r2[q]) + bf2f(r3[q]));
  }
  if (j + SLOTS < end) {
    int i0 = col[j], i1 = col[j + SLOTS];
    u16x8 r0 = Hv[(size_t)i0 * LPN + li];
    u16x8 r1 = Hv[(size_t)i1 * LPN + li];
#pragma unroll
    for (int q = 0; q < 8; ++q) s[q] += bf2f(r0[q]) + bf2f(r1[q]);
    j += 2 * SLOTS;
  }
  if (j < end) {
    int i0 = col[j];
    u16x8 r0 = Hv[(size_t)i0 * LPN + li];
#pragma unroll
    for (int q = 0; q < 8; ++q) s[q] += bf2f(r0[q]);
  }
#pragma unroll
  for (int off = LPN; off < 64; off <<= 1) {
#pragma unroll
    for (int q = 0; q < 8; ++q) s[q] += __shfl_xor(s[q], off);
  }
  if (slot == 0) {
    const float4* bv = reinterpret_cast<const float4*>(bias) + li * 2;
    float4 b0 = bv[0], b1 = bv[1];
    float sv[8];
#pragma unroll
    for (int q = 0; q < 8; ++q) sv[q] = (s[q] + bf2f(h0[q])) * di;
    sv[0] += b0.x; sv[1] += b0.y; sv[2] += b0.z; sv[3] += b0.w;
    sv[4] += b1.x; sv[5] += b1.y; sv[6] += b1.z; sv[7] += b1.w;
    if (RELU) {
#pragma unroll
      for (int q = 0; q < 8; ++q) sv[q] = fmaxf(sv[q], 0.f);
    }
    if constexpr (OUT_BF16) {
      u16x8 pk;
#pragma unroll
      for (int q = 0; q < 8; ++q) pk[q] = f2bf(sv[q]);
      reinterpret_cast<u16x8*>(out)[(size_t)node * LPN + li] = pk;
    } else {
      float4* ov = reinterpret_cast<float4*>(out) + (size_t)node * LPN * 2 + li * 2;
      ov[0] = make_float4(sv[0], sv[1], sv[2], sv[3]);
      ov[1] = make_float4(sv[4], sv[5], sv[6], sv[7]);
    }
  }
}

// ----------------- fused agg (F=64) + log_softmax --------------------------
__global__ void agg_ls_kernel(const unsigned short* __restrict__ H,
                              const int* __restrict__ row_ptr, const int* __restrict__ col,
                              const float* __restrict__ dinv, const float* __restrict__ bias,
                              float* __restrict__ out, int N) {
  constexpr int LPN = 8;   // 8 lanes x 8 feats = 64
  constexpr int SLOTS = 8;
  const int tid = threadIdx.x;
  const int lane = tid & 63;
  const int li = lane & (LPN - 1);
  const int slot = lane / LPN;
  const int node = blockIdx.x * 4 + (tid >> 6);
  if (node >= N) return;
  const float di = dinv[node];
  const u16x8* Hv = reinterpret_cast<const u16x8*>(H);
  u16x8 h0 = Hv[(size_t)node * LPN + li];

  float s[8];
#pragma unroll
  for (int q = 0; q < 8; ++q) s[q] = 0.f;

  const int beg = row_ptr[node];
  const int end = row_ptr[node + 1];
  int j = beg + slot;
  for (; j + 3 * SLOTS < end; j += 4 * SLOTS) {
    int i0 = col[j], i1 = col[j + SLOTS], i2 = col[j + 2 * SLOTS], i3 = col[j + 3 * SLOTS];
    u16x8 r0 = Hv[(size_t)i0 * LPN + li];
    u16x8 r1 = Hv[(size_t)i1 * LPN + li];
    u16x8 r2 = Hv[(size_t)i2 * LPN + li];
    u16x8 r3 = Hv[(size_t)i3 * LPN + li];
#pragma unroll
    for (int q = 0; q < 8; ++q)
      s[q] += (bf2f(r0[q]) + bf2f(r1[q])) + (bf2f(r2[q]) + bf2f(r3[q]));
  }
  if (j + SLOTS < end) {
    int i0 = col[j], i1 = col[j + SLOTS];
    u16x8 r0 = Hv[(size_t)i0 * LPN + li];
    u16x8 r1 = Hv[(size_t)i1 * LPN + li];
#pragma unroll
    for (int q = 0; q < 8; ++q) s[q] += bf2f(r0[q]) + bf2f(r1[q]);
    j += 2 * SLOTS;
  }
  if (j < end) {
    int i0 = col[j];
    u16x8 r0 = Hv[(size_t)i0 * LPN + li];
#pragma unroll
    for (int q = 0; q < 8; ++q) s[q] += bf2f(r0[q]);
  }
#pragma unroll
  for (int off = LPN; off < 64; off <<= 1) {
#pragma unroll
    for (int q = 0; q < 8; ++q) s[q] += __shfl_xor(s[q], off);
  }
  // lanes 0..7 (slot 0) hold the 64 logits; fused log_softmax
  float v[8];
  const float4* bv = reinterpret_cast<const float4*>(bias) + li * 2;
  float4 b0 = bv[0], b1 = bv[1];
#pragma unroll
  for (int q = 0; q < 8; ++q) v[q] = (s[q] + bf2f(h0[q])) * di;
  v[0] += b0.x; v[1] += b0.y; v[2] += b0.z; v[3] += b0.w;
  v[4] += b1.x; v[5] += b1.y; v[6] += b1.z; v[7] += b1.w;
  float m = v[0];
#pragma unroll
  for (int q = 1; q < 8; ++q) m = fmaxf(m, v[q]);
#pragma unroll
  for (int off = 1; off < 8; off <<= 1) m = fmaxf(m, __shfl_xor(m, off));
  float es = 0.f;
#pragma unroll
  for (int q = 0; q < 8; ++q) es += expf(v[q] - m);
#pragma unroll
  for (int off = 1; off < 8; off <<= 1) es += __shfl_xor(es, off);
  if (slot == 0) {
    float lse = m + logf(es);
    float4* ov = reinterpret_cast<float4*>(out) + (size_t)node * 16 + li * 2;
    ov[0] = make_float4(v[0] - lse, v[1] - lse, v[2] - lse, v[3] - lse);
    ov[1] = make_float4(v[4] - lse, v[5] - lse, v[6] - lse, v[7] - lse);
  }
}

// ---------------------------------------------------------------------------
extern "C" void kernel_launch(void* const* d_in, const int* in_sizes, int n_in,
                              void* d_out, int out_size, void* d_ws, size_t ws_size,
                              hipStream_t stream) {
  const float* x  = (const float*)d_in[0];
  const int*   ei = (const int*)d_in[1];
  const float* W1 = (const float*)d_in[2];
  const float* b1 = (const float*)d_in[3];
  const float* W2 = (const float*)d_in[4];
  const float* b2 = (const float*)d_in[5];
  const float* W3 = (const float*)d_in[6];
  const float* b3 = (const float*)d_in[7];
  float* out = (float*)d_out;

  const int N = in_sizes[0] / NFEAT;  // 50000
  const int E = in_sizes[1] / 2;      // 800000
  const int* src = ei;
  const int* dst = ei + E;

  char* ws = (char*)d_ws;
  size_t off = 0;
  auto nxt = [&](size_t bytes) -> void* {
    void* p = ws + off;
    off += (bytes + 255) & ~(size_t)255;
    return p;
  };
  const int NB = (N + 255) / 256;
  int*   cnt     = (int*)nxt((size_t)N * 4);
  int*   pos     = (int*)nxt((size_t)N * 4);
  int*   row_ptr = (int*)nxt((size_t)(N + 1) * 4);
  int*   col     = (int*)nxt((size_t)E * 4);
  float* dinv    = (float*)nxt((size_t)N * 4);
  int*   bsum    = (int*)nxt((size_t)NB * 4);
  int*   boff    = (int*)nxt((size_t)NB * 4);
  unsigned short* zbuf = (unsigned short*)nxt((size_t)N * NHID * 2);  // GEMM out (scaled bf16)
  unsigned short* hb16 = (unsigned short*)nxt((size_t)N * NHID * 2);  // agg out (bf16)
  unsigned short* Wt1 = (unsigned short*)nxt((size_t)NHID * NFEAT * 2);
  unsigned short* Wt2 = (unsigned short*)nxt((size_t)NHID * NHID * 2);
  unsigned short* Wt3 = (unsigned short*)nxt((size_t)NCLS * NHID * 2);
  (void)ws_size; (void)n_in; (void)out_size;

  const int GB = (N + 63) / 64;       // 782 GEMM blocks
  const int EB = (E + 255) / 256;     // 3125 edge blocks
  const int ablocks = (N + 3) / 4;

  // setup: zero cnt + wcast W1/W2/W3  (196 + 256 + 64 + 32 blocks)
  setup_kernel<<<NB + 256 + 64 + 32, 256, 0, stream>>>(cnt, NB, N, W1, Wt1, W2, Wt2, W3, Wt3);
  count_kernel<<<EB, 256, 0, stream>>>(dst, cnt, E);
  dinv_partials_kernel<<<NB, 256, 0, stream>>>(cnt, dinv, bsum, N);
  scan_bsums_kernel<<<1, 256, 0, stream>>>(bsum, boff, NB);
  scan_final_kernel<<<NB, 256, 0, stream>>>(cnt, boff, row_ptr, pos, N, E);

  // GEMM1 (scaled) co-scheduled with CSR fill
  gemm1_fill_kernel<<<GB + EB, 256, 0, stream>>>(x, Wt1, dinv, zbuf, N, src, dst, pos, col, E, GB);
  agg_kernel<128, 1, true><<<ablocks, 256, 0, stream>>>(zbuf, row_ptr, col, dinv, b1, hb16, N);

  mfma_gemm_kernel<128, true><<<GB, 256, 0, stream>>>(hb16, Wt2, dinv, zbuf, N, NHID);
  agg_kernel<128, 1, true><<<ablocks, 256, 0, stream>>>(zbuf, row_ptr, col, dinv, b2, hb16, N);

  mfma_gemm_kernel<64, true><<<GB, 256, 0, stream>>>(hb16, Wt3, dinv, zbuf, N, NHID);
  agg_ls_kernel<<<ablocks, 256, 0, stream>>>(zbuf, row_ptr, col, dinv, b3, out, N);
}